// Round 1
// 606.597 us; speedup vs baseline: 1.0152x; 1.0152x over previous
//
#include <hip/hip_runtime.h>
#include <hip/hip_fp16.h>

namespace {
constexpr int C    = 150;
constexpr int HW   = 384 * 512;            // 196608
constexpr int NPIX = 4 * HW;               // 786432
constexpr long CHW = (long)C * HW;
constexpr int TPB  = 512;                  // 8 waves/block
constexpr int PPT  = 2;                    // pixels per thread (float2 loads)
constexpr int NBLK = NPIX / (TPB * PPT);   // 768 -> exactly 3 blocks/CU, 24 waves/CU
constexpr int WSTR = 154;                  // LDS weight row stride in halves:
                                           // 77 words, gcd(77,32)=1 -> uniform banks,
                                           // rows 4B-aligned for half2 reads
}

// Per-block partials: part[2b] = sum m*(LSE - dot), part[2b+1] = sum m
__global__ __launch_bounds__(TPB, 6) void wcel_main(
    const float* __restrict__ pred,
    const int*   __restrict__ gtb,
    const float* __restrict__ mask,
    const float* __restrict__ weight,
    float* __restrict__ part)
{
    __shared__ __half wlds[C * WSTR];       // 46.2 KB -> 3 blocks/CU (LDS-limited)
    __shared__ float rn[TPB / 64], rv[TPB / 64];

    // stage weight fp32->fp16 into LDS with padded row stride
    for (int i = threadIdx.x; i < C * C; i += TPB) {
        int row = i / C;                     // compiler magic-mul
        int col = i - row * C;
        wlds[row * WSTR + col] = __float2half(weight[i]);
    }
    __syncthreads();

    int p = (blockIdx.x * TPB + threadIdx.x) * PPT;
    int b = p / HW;                          // waves never straddle b (HW % 1024 == 0)
    int r = p - b * HW;
    const float* base = pred + (size_t)b * CHW + r;

    float2 m2 = *(const float2*)(mask + p);
    int2   g2 = *(const int2*)(gtb + p);
    const __half2* w0 = (const __half2*)(wlds + g2.x * WSTR);
    const __half2* w1 = (const __half2*)(wlds + g2.y * WSTR);

    // split accumulator chains (even/odd channel) to halve dep-chain length
    float sa0 = 0.f, sb0 = 0.f, sa1 = 0.f, sb1 = 0.f;
    float da0 = 0.f, db0 = 0.f, da1 = 0.f, db1 = 0.f;

    #pragma unroll 5
    for (int cp = 0; cp < C / 2; ++cp) {
        float2 xa = *(const float2*)(base + (size_t)(2 * cp) * HW);
        float2 xb = *(const float2*)(base + (size_t)(2 * cp + 1) * HW);
        float2 v0 = __half22float2(w0[cp]);   // {w[g0,2cp], w[g0,2cp+1]}
        float2 v1 = __half22float2(w1[cp]);

        da0 = fmaf(v0.x, xa.x, da0); db0 = fmaf(v0.y, xb.x, db0);
        da1 = fmaf(v1.x, xa.y, da1); db1 = fmaf(v1.y, xb.y, db1);

        sa0 += __expf(xa.x); sb0 += __expf(xb.x);
        sa1 += __expf(xa.y); sb1 += __expf(xb.y);
    }

    float num = m2.x * (__logf(sa0 + sb0) - (da0 + db0))
              + m2.y * (__logf(sa1 + sb1) - (da1 + db1));
    float val = m2.x + m2.y;

    // wave-64 shuffle reduction
    #pragma unroll
    for (int off = 32; off > 0; off >>= 1) {
        num += __shfl_down(num, off);
        val += __shfl_down(val, off);
    }
    int lane = threadIdx.x & 63, wid = threadIdx.x >> 6;
    if (lane == 0) { rn[wid] = num; rv[wid] = val; }
    __syncthreads();
    if (threadIdx.x == 0) {
        float n = 0.f, v = 0.f;
        #pragma unroll
        for (int i = 0; i < TPB / 64; ++i) { n += rn[i]; v += rv[i]; }
        part[2 * blockIdx.x]     = n;   // full overwrite: no memset, no atomics
        part[2 * blockIdx.x + 1] = v;
    }
}

__global__ __launch_bounds__(256) void wcel_final(const float* __restrict__ part,
                                                  float* __restrict__ out)
{
    __shared__ float rn[4], rv[4];
    float n = 0.f, v = 0.f;
    #pragma unroll
    for (int k = 0; k < NBLK / 256; ++k) {
        float2 pv = ((const float2*)part)[threadIdx.x + k * 256];
        n += pv.x; v += pv.y;
    }
    #pragma unroll
    for (int off = 32; off > 0; off >>= 1) {
        n += __shfl_down(n, off);
        v += __shfl_down(v, off);
    }
    int lane = threadIdx.x & 63, wid = threadIdx.x >> 6;
    if (lane == 0) { rn[wid] = n; rv[wid] = v; }
    __syncthreads();
    if (threadIdx.x == 0) {
        float nn = rn[0] + rn[1] + rn[2] + rn[3];
        float vv = rv[0] + rv[1] + rv[2] + rv[3];
        out[0] = nn / vv;
    }
}

extern "C" void kernel_launch(void* const* d_in, const int* in_sizes, int n_in,
                              void* d_out, int out_size, void* d_ws, size_t ws_size,
                              hipStream_t stream)
{
    const float* pred   = (const float*)d_in[0];  // [B,C,H,W] fp32
    const int*   gtb    = (const int*)  d_in[1];  // [B,1,H,W] int32
    // d_in[2] = gt (unused by the loss math)
    const float* mask   = (const float*)d_in[3];  // [B,1,H,W] fp32 0/1
    const float* weight = (const float*)d_in[4];  // [C,C] fp32 row-normalized
    float* part = (float*)d_ws;                   // [NBLK][2] partials

    wcel_main<<<NBLK, TPB, 0, stream>>>(pred, gtb, mask, weight, part);
    wcel_final<<<1, 256, 0, stream>>>(part, (float*)d_out);
}